// Round 1
// baseline (152.799 us; speedup 1.0000x reference)
//
#include <hip/hip_runtime.h>
#include <hip/hip_bf16.h>
#include <cstdint>
#include <math.h>

#define LSEQ 2048
#define BATCH 2
#define NHEAD 16
#define DHEAD 64
#define DMODEL 1024
#define ROWS (BATCH*LSEQ)

typedef __bf16 bf16x8 __attribute__((ext_vector_type(8)));
typedef float f32x4 __attribute__((ext_vector_type(4)));
typedef unsigned short u16;

__device__ __forceinline__ u16 f2bf(float f) {
  unsigned int u = __float_as_uint(f);
  u += 0x7fffu + ((u >> 16) & 1u);
  return (u16)(u >> 16);
}

// ---------------- transpose + fp32->bf16 convert: out[c][r] = bf16(in[r][c]) ----
__global__ void k_transpose_cvt(const float* __restrict__ in, u16* __restrict__ out, int R, int C) {
  __shared__ float tile[32][33];
  int c0 = blockIdx.x * 32, r0 = blockIdx.y * 32;
  int tx = threadIdx.x, ty = threadIdx.y;
#pragma unroll
  for (int i = 0; i < 32; i += 8)
    tile[ty + i][tx] = in[(size_t)(r0 + ty + i) * C + (c0 + tx)];
  __syncthreads();
#pragma unroll
  for (int i = 0; i < 32; i += 8)
    out[(size_t)(c0 + ty + i) * R + (r0 + tx)] = f2bf(tile[tx][ty + i]);
}

// ---------------- RoPE tables: cos/sin [LSEQ][32] ------------------------------
__global__ void k_rope_tables(float* __restrict__ cosb, float* __restrict__ sinb) {
  int idx = blockIdx.x * blockDim.x + threadIdx.x;
  if (idx >= LSEQ * 32) return;
  int l = idx >> 5, f = idx & 31;
  double inv = pow(10000.0, -(double)f / 32.0);
  float ang = (float)l * (float)inv;
  cosb[idx] = cosf(ang);
  sinb[idx] = sinf(ang);
}

// ---------------- segment bounds: bnd[b][s] = lower_bound(seq[b], s), s=0..4 ---
__global__ void k_bounds(const int* __restrict__ seq, int* __restrict__ bnd) {
  int t = threadIdx.x;
  if (t < BATCH * 5) {
    int b = t / 5, s = t % 5;
    const int* row = seq + b * LSEQ;
    int lo = 0, hi = LSEQ;
    while (lo < hi) { int mid = (lo + hi) >> 1; if (row[mid] < s) lo = mid + 1; else hi = mid; }
    bnd[b * 5 + s] = lo;
  }
}

// ---------------- LN1: h = bf16(layernorm(x, w, b)) ----------------------------
__global__ __launch_bounds__(256) void k_ln1(const float* __restrict__ x, const float* __restrict__ w,
                                             const float* __restrict__ bias, u16* __restrict__ h) {
  int row = blockIdx.x, t = threadIdx.x;
  const float4 xv = ((const float4*)(x + (size_t)row * DMODEL))[t];
  float s = xv.x + xv.y + xv.z + xv.w;
  float s2 = xv.x * xv.x + xv.y * xv.y + xv.z * xv.z + xv.w * xv.w;
#pragma unroll
  for (int m2 = 1; m2 < 64; m2 <<= 1) { s += __shfl_xor(s, m2); s2 += __shfl_xor(s2, m2); }
  __shared__ float rb[2][4];
  int wv = t >> 6;
  if ((t & 63) == 0) { rb[0][wv] = s; rb[1][wv] = s2; }
  __syncthreads();
  s  = rb[0][0] + rb[0][1] + rb[0][2] + rb[0][3];
  s2 = rb[1][0] + rb[1][1] + rb[1][2] + rb[1][3];
  float mu = s * (1.0f / DMODEL);
  float rs = rsqrtf(s2 * (1.0f / DMODEL) - mu * mu + 1e-5f);
  const float4 wv4 = ((const float4*)w)[t];
  const float4 bv4 = ((const float4*)bias)[t];
  ushort4 o;
  o.x = f2bf((xv.x - mu) * rs * wv4.x + bv4.x);
  o.y = f2bf((xv.y - mu) * rs * wv4.y + bv4.y);
  o.z = f2bf((xv.z - mu) * rs * wv4.z + bv4.z);
  o.w = f2bf((xv.w - mu) * rs * wv4.w + bv4.w);
  ((ushort4*)(h + (size_t)row * DMODEL))[t] = o;
}

// ---------------- bf16 GEMM: C[M][N] = A[M][K] @ BT[N][K]^T, fp32 out ----------
__global__ __launch_bounds__(256) void k_gemm_bt(const u16* __restrict__ A, const u16* __restrict__ B,
                                                 float* __restrict__ C, int M, int N, int K) {
  __shared__ u16 As[128 * 64];
  __shared__ u16 Bs[128 * 64];
  const int t = threadIdx.x;
  const int lane = t & 63, w = t >> 6;
  const int m0 = blockIdx.y * 128, n0 = blockIdx.x * 128;
  const int wm = (w >> 1) * 64, wn = (w & 1) * 64;
  const int NT = K >> 6;

  f32x4 acc[4][4] = {};
  bf16x8 ra[4], rb[4];
  const u16* Ap = A + (size_t)m0 * K;
  const u16* Bp = B + (size_t)n0 * K;
#pragma unroll
  for (int j = 0; j < 4; j++) {
    int c = t + 256 * j, row = c >> 3, cb = c & 7;
    ra[j] = *(const bf16x8*)(Ap + (size_t)row * K + cb * 8);
    rb[j] = *(const bf16x8*)(Bp + (size_t)row * K + cb * 8);
  }
  for (int kt = 0; kt < NT; kt++) {
    __syncthreads();
#pragma unroll
    for (int j = 0; j < 4; j++) {
      int c = t + 256 * j, row = c >> 3, cb = c & 7;
      *(bf16x8*)((char*)As + row * 128 + ((cb * 16) ^ ((row & 7) << 4))) = ra[j];
      *(bf16x8*)((char*)Bs + row * 128 + ((cb * 16) ^ ((row & 7) << 4))) = rb[j];
    }
    __syncthreads();
    if (kt + 1 < NT) {
      const u16* Ap2 = Ap + (kt + 1) * 64;
      const u16* Bp2 = Bp + (kt + 1) * 64;
#pragma unroll
      for (int j = 0; j < 4; j++) {
        int c = t + 256 * j, row = c >> 3, cb = c & 7;
        ra[j] = *(const bf16x8*)(Ap2 + (size_t)row * K + cb * 8);
        rb[j] = *(const bf16x8*)(Bp2 + (size_t)row * K + cb * 8);
      }
    }
#pragma unroll
    for (int kk = 0; kk < 2; kk++) {
      bf16x8 af[4], bfr[4];
#pragma unroll
      for (int i = 0; i < 4; i++) {
        int rowa = wm + i * 16 + (lane & 15);
        af[i] = *(const bf16x8*)((char*)As + rowa * 128 + ((kk * 64 + (lane >> 4) * 16) ^ ((rowa & 7) << 4)));
        int rowb = wn + i * 16 + (lane & 15);
        bfr[i] = *(const bf16x8*)((char*)Bs + rowb * 128 + ((kk * 64 + (lane >> 4) * 16) ^ ((rowb & 7) << 4)));
      }
#pragma unroll
      for (int mf = 0; mf < 4; mf++)
#pragma unroll
        for (int nf = 0; nf < 4; nf++)
          acc[mf][nf] = __builtin_amdgcn_mfma_f32_16x16x32_bf16(af[mf], bfr[nf], acc[mf][nf], 0, 0, 0);
    }
  }
  const int cr = (lane >> 4) * 4, cc = lane & 15;
#pragma unroll
  for (int mf = 0; mf < 4; mf++)
#pragma unroll
    for (int nf = 0; nf < 4; nf++) {
      float* Cp = C + (size_t)(m0 + wm + mf * 16 + cr) * N + (n0 + wn + nf * 16 + cc);
#pragma unroll
      for (int r = 0; r < 4; r++) Cp[(size_t)r * N] = acc[mf][nf][r];
    }
}

// ---------------- q/k layernorm (over full D) + RoPE + split to heads ----------
__global__ __launch_bounds__(256) void k_qk_ln_rope(const float* __restrict__ qkv,
                                                    const float* __restrict__ qw, const float* __restrict__ kw,
                                                    const float* __restrict__ cosb, const float* __restrict__ sinb,
                                                    u16* __restrict__ Q, u16* __restrict__ K, u16* __restrict__ V) {
  int row = blockIdx.x, t = threadIdx.x;
  int b = row >> 11, l = row & 2047;
  const float* base = qkv + (size_t)row * 3072;
  float4 qv = ((const float4*)base)[t];
  float4 kv = ((const float4*)(base + 1024))[t];
  float4 vv = ((const float4*)(base + 2048))[t];
  float red[4];
  red[0] = qv.x + qv.y + qv.z + qv.w;
  red[1] = qv.x * qv.x + qv.y * qv.y + qv.z * qv.z + qv.w * qv.w;
  red[2] = kv.x + kv.y + kv.z + kv.w;
  red[3] = kv.x * kv.x + kv.y * kv.y + kv.z * kv.z + kv.w * kv.w;
#pragma unroll
  for (int i = 0; i < 4; i++)
#pragma unroll
    for (int m2 = 1; m2 < 64; m2 <<= 1) red[i] += __shfl_xor(red[i], m2);
  __shared__ float rb[4][4];
  int w = t >> 6;
  if ((t & 63) == 0) { rb[w][0] = red[0]; rb[w][1] = red[1]; rb[w][2] = red[2]; rb[w][3] = red[3]; }
  __syncthreads();
  float S1 = rb[0][0] + rb[1][0] + rb[2][0] + rb[3][0];
  float S2 = rb[0][1] + rb[1][1] + rb[2][1] + rb[3][1];
  float S3 = rb[0][2] + rb[1][2] + rb[2][2] + rb[3][2];
  float S4 = rb[0][3] + rb[1][3] + rb[2][3] + rb[3][3];
  float muq = S1 * (1.0f / DMODEL), rsq = rsqrtf(S2 * (1.0f / DMODEL) - muq * muq + 1e-5f);
  float muk = S3 * (1.0f / DMODEL), rsk = rsqrtf(S4 * (1.0f / DMODEL) - muk * muk + 1e-5f);
  __shared__ float qs[1024], ks[1024];
  float4 qwv = ((const float4*)qw)[t];
  float4 kwv = ((const float4*)kw)[t];
  qs[t * 4 + 0] = (qv.x - muq) * rsq * qwv.x;  ks[t * 4 + 0] = (kv.x - muk) * rsk * kwv.x;
  qs[t * 4 + 1] = (qv.y - muq) * rsq * qwv.y;  ks[t * 4 + 1] = (kv.y - muk) * rsk * kwv.y;
  qs[t * 4 + 2] = (qv.z - muq) * rsq * qwv.z;  ks[t * 4 + 2] = (kv.z - muk) * rsk * kwv.z;
  qs[t * 4 + 3] = (qv.w - muq) * rsq * qwv.w;  ks[t * 4 + 3] = (kv.w - muk) * rsk * kwv.w;
  __syncthreads();
  int d0 = t * 4;
  int hh = d0 >> 6;
  union { ushort4 v4; u16 e[4]; } qo, ko, vo;
  const float* vp = &vv.x;
#pragma unroll
  for (int i = 0; i < 4; i++) {
    int d = d0 + i, dd = d & 63, fr = dd & 31;
    float c = cosb[l * 32 + fr], s = sinb[l * 32 + fr];
    float q1 = qs[d], q2 = (dd < 32) ? -qs[d + 32] : qs[d - 32];
    float k1 = ks[d], k2 = (dd < 32) ? -ks[d + 32] : ks[d - 32];
    qo.e[i] = f2bf(q1 * c + q2 * s);
    ko.e[i] = f2bf(k1 * c + k2 * s);
    vo.e[i] = f2bf(vp[i]);
  }
  size_t oidx = ((size_t)(b * NHEAD + hh) * LSEQ + l) * DHEAD + (d0 & 63);
  *(ushort4*)(Q + oidx) = qo.v4;
  *(ushort4*)(K + oidx) = ko.v4;
  *(ushort4*)(V + oidx) = vo.v4;
}

// ---------------- segment-masked flash attention -------------------------------
__global__ __launch_bounds__(256) void k_attn(const u16* __restrict__ Q, const u16* __restrict__ Kb,
                                              const u16* __restrict__ Vb, const int* __restrict__ seq,
                                              const int* __restrict__ bnd, u16* __restrict__ ctx) {
  __shared__ u16 Ks[64 * 64];
  __shared__ u16 Vt[64 * 64];
  __shared__ u16 Ps[4][32 * 64];
  __shared__ int kseq[64];

  const int bid = blockIdx.x;
  const int qt = bid & 15, h = (bid >> 4) & 15, b = bid >> 8;
  const int t = threadIdx.x, lane = t & 63, w = t >> 6;
  const int q0 = qt * 128;
  const size_t hoff = (size_t)(b * NHEAD + h) * LSEQ * DHEAD;
  const u16* Qg = Q + hoff;
  const u16* Kg = Kb + hoff;
  const u16* Vg = Vb + hoff;
  const int* seqb = seq + b * LSEQ;

  const int qrow_lo = q0 + w * 32;
  bf16x8 qf[2][2];
#pragma unroll
  for (int mf = 0; mf < 2; mf++)
#pragma unroll
    for (int kk = 0; kk < 2; kk++)
      qf[mf][kk] = *(const bf16x8*)(Qg + (size_t)(qrow_lo + mf * 16 + (lane & 15)) * 64 + kk * 32 + (lane >> 4) * 8);

  int qsq[2][4];
#pragma unroll
  for (int mf = 0; mf < 2; mf++)
#pragma unroll
    for (int r = 0; r < 4; r++)
      qsq[mf][r] = seqb[qrow_lo + mf * 16 + (lane >> 4) * 4 + r];

  float m_[2][4], ls[2][4];
  f32x4 acc[2][4] = {};
#pragma unroll
  for (int mf = 0; mf < 2; mf++)
#pragma unroll
    for (int r = 0; r < 4; r++) { m_[mf][r] = -1e30f; ls[mf][r] = 0.f; }

  int smin = seqb[q0], smax = seqb[q0 + 127];
  int kbeg = bnd[b * 5 + smin] & ~63;
  int kend = (bnd[b * 5 + smax + 1] + 63) & ~63;
  if (kend > LSEQ) kend = LSEQ;

  for (int kt = kbeg; kt < kend; kt += 64) {
    __syncthreads();
#pragma unroll
    for (int j = 0; j < 2; j++) {
      int c = t + 256 * j, row = c >> 3, cb = c & 7;
      *(bf16x8*)((char*)Ks + row * 128 + ((cb * 16) ^ ((row & 7) << 4))) =
          *(const bf16x8*)(Kg + (size_t)(kt + row) * 64 + cb * 8);
    }
#pragma unroll
    for (int j = 0; j < 2; j++) {
      int c = t + 256 * j, key = c >> 3, db = c & 7;
      union { bf16x8 v; u16 e[8]; } vv;
      vv.v = *(const bf16x8*)(Vg + (size_t)(kt + key) * 64 + db * 8);
#pragma unroll
      for (int i = 0; i < 8; i++) {
        int d = db * 8 + i;
        int sl = ((d ^ (d >> 3)) & 7) << 4;
        *(u16*)((char*)Vt + d * 128 + ((key * 2) ^ sl)) = vv.e[i];
      }
    }
    if (t < 64) kseq[t] = seqb[kt + t];
    __syncthreads();

    f32x4 s[2][4] = {};
#pragma unroll
    for (int kk = 0; kk < 2; kk++) {
      bf16x8 kf[4];
#pragma unroll
      for (int nf = 0; nf < 4; nf++) {
        int rowk = nf * 16 + (lane & 15);
        kf[nf] = *(const bf16x8*)((char*)Ks + rowk * 128 + ((kk * 64 + (lane >> 4) * 16) ^ ((rowk & 7) << 4)));
      }
#pragma unroll
      for (int mf = 0; mf < 2; mf++)
#pragma unroll
        for (int nf = 0; nf < 4; nf++)
          s[mf][nf] = __builtin_amdgcn_mfma_f32_16x16x32_bf16(qf[mf][kk], kf[nf], s[mf][nf], 0, 0, 0);
    }

    int ksq[4];
#pragma unroll
    for (int nf = 0; nf < 4; nf++) ksq[nf] = kseq[nf * 16 + (lane & 15)];

#pragma unroll
    for (int mf = 0; mf < 2; mf++) {
#pragma unroll
      for (int r = 0; r < 4; r++) {
        float sv[4]; float mx = -1e30f;
#pragma unroll
        for (int nf = 0; nf < 4; nf++) {
          sv[nf] = (ksq[nf] == qsq[mf][r]) ? s[mf][nf][r] * 0.125f : -1e30f;
          mx = fmaxf(mx, sv[nf]);
        }
#pragma unroll
        for (int d2 = 1; d2 < 16; d2 <<= 1) mx = fmaxf(mx, __shfl_xor(mx, d2));
        float mnew = fmaxf(m_[mf][r], mx);
        float gate = (mnew > -1e29f) ? 1.f : 0.f;
        float alpha = __expf(m_[mf][r] - mnew);
        m_[mf][r] = mnew;
        float pv[4]; float rsum = 0.f;
#pragma unroll
        for (int nf = 0; nf < 4; nf++) { pv[nf] = gate * __expf(sv[nf] - mnew); rsum += pv[nf]; }
#pragma unroll
        for (int d2 = 1; d2 < 16; d2 <<= 1) rsum += __shfl_xor(rsum, d2);
        ls[mf][r] = ls[mf][r] * alpha + rsum;
#pragma unroll
        for (int df = 0; df < 4; df++) acc[mf][df][r] *= alpha;
        int prow = mf * 16 + (lane >> 4) * 4 + r;
#pragma unroll
        for (int nf = 0; nf < 4; nf++)
          *(u16*)((char*)&Ps[w][0] + prow * 128 + (((nf * 16 + (lane & 15)) * 2) ^ ((prow & 7) << 4))) = f2bf(pv[nf]);
      }
    }

#pragma unroll
    for (int kk = 0; kk < 2; kk++) {
      bf16x8 pa[2], vbr[4];
#pragma unroll
      for (int mf = 0; mf < 2; mf++) {
        int prow = mf * 16 + (lane & 15);
        pa[mf] = *(const bf16x8*)((char*)&Ps[w][0] + prow * 128 + ((kk * 64 + (lane >> 4) * 16) ^ ((prow & 7) << 4)));
      }
#pragma unroll
      for (int df = 0; df < 4; df++) {
        int d = df * 16 + (lane & 15);
        int sl = ((d ^ (d >> 3)) & 7) << 4;
        vbr[df] = *(const bf16x8*)((char*)Vt + d * 128 + ((kk * 64 + (lane >> 4) * 16) ^ sl));
      }
#pragma unroll
      for (int mf = 0; mf < 2; mf++)
#pragma unroll
        for (int df = 0; df < 4; df++)
          acc[mf][df] = __builtin_amdgcn_mfma_f32_16x16x32_bf16(pa[mf], vbr[df], acc[mf][df], 0, 0, 0);
    }
  }

#pragma unroll
  for (int mf = 0; mf < 2; mf++)
#pragma unroll
    for (int df = 0; df < 4; df++)
#pragma unroll
      for (int r = 0; r < 4; r++) {
        int qrow = qrow_lo + mf * 16 + (lane >> 4) * 4 + r;
        float ov = acc[mf][df][r] / ls[mf][r];
        ctx[(size_t)(b * LSEQ + qrow) * DMODEL + h * 64 + df * 16 + (lane & 15)] = f2bf(ov);
      }
}

// ---------------- launch --------------------------------------------------------
extern "C" void kernel_launch(void* const* d_in, const int* in_sizes, int n_in,
                              void* d_out, int out_size, void* d_ws, size_t ws_size,
                              hipStream_t stream) {
  const float* x    = (const float*)d_in[0];
  const int*   seq  = (const int*)d_in[1];
  const float* ln1w = (const float*)d_in[2];
  const float* ln1b = (const float*)d_in[3];
  const float* wqkv = (const float*)d_in[4];
  const float* qlnw = (const float*)d_in[5];
  const float* klnw = (const float*)d_in[6];
  const float* wout = (const float*)d_in[7];
  float* out = (float*)d_out;

  char* p = (char*)d_ws;
  u16* wqkvT = (u16*)p;  p += (size_t)3072 * 1024 * 2;
  u16* woutT = (u16*)p;  p += (size_t)1024 * 1024 * 2;
  u16* hbuf  = (u16*)p;  p += (size_t)ROWS * DMODEL * 2;
  u16* Qb    = (u16*)p;  p += (size_t)ROWS * DMODEL * 2;
  u16* Kbuf  = (u16*)p;  p += (size_t)ROWS * DMODEL * 2;
  u16* Vbuf  = (u16*)p;  p += (size_t)ROWS * DMODEL * 2;
  u16* ctxb  = (u16*)p;  p += (size_t)ROWS * DMODEL * 2;
  float* cosb = (float*)p; p += (size_t)LSEQ * 32 * 4;
  float* sinb = (float*)p; p += (size_t)LSEQ * 32 * 4;
  int* bnd   = (int*)p;  p += 256;
  float* qkv = (float*)p; p += (size_t)ROWS * 3072 * 4;

  k_transpose_cvt<<<dim3(3072 / 32, 1024 / 32), dim3(32, 8), 0, stream>>>(wqkv, wqkvT, 1024, 3072);
  k_transpose_cvt<<<dim3(1024 / 32, 1024 / 32), dim3(32, 8), 0, stream>>>(wout, woutT, 1024, 1024);
  k_rope_tables<<<(LSEQ * 32) / 256, 256, 0, stream>>>(cosb, sinb);
  k_bounds<<<1, 64, 0, stream>>>(seq, bnd);
  k_ln1<<<ROWS, 256, 0, stream>>>(x, ln1w, ln1b, hbuf);
  k_gemm_bt<<<dim3(3072 / 128, ROWS / 128), 256, 0, stream>>>(hbuf, wqkvT, qkv, ROWS, 3072, 1024);
  k_qk_ln_rope<<<ROWS, 256, 0, stream>>>(qkv, qlnw, klnw, cosb, sinb, Qb, Kbuf, Vbuf);
  k_attn<<<BATCH * NHEAD * (LSEQ / 128), 256, 0, stream>>>(Qb, Kbuf, Vbuf, seq, bnd, ctxb);
  k_gemm_bt<<<dim3(1024 / 128, ROWS / 128), 256, 0, stream>>>(ctxb, woutT, out, ROWS, 1024, 1024);
}

// Round 2
// 147.785 us; speedup vs baseline: 1.0339x; 1.0339x over previous
//
#include <hip/hip_runtime.h>
#include <hip/hip_bf16.h>
#include <cstdint>
#include <math.h>

#define LSEQ 2048
#define BATCH 2
#define NHEAD 16
#define DHEAD 64
#define DMODEL 1024
#define ROWS (BATCH*LSEQ)

typedef __bf16 bf16x8 __attribute__((ext_vector_type(8)));
typedef float f32x4 __attribute__((ext_vector_type(4)));
typedef unsigned short u16;

#define GLD(lds_base, src_g) \
  __builtin_amdgcn_global_load_lds((const __attribute__((address_space(1))) void*)(src_g), \
                                   (__attribute__((address_space(3))) void*)(lds_base), 16, 0, 0)

__device__ __forceinline__ u16 f2bf(float f) {
  unsigned int u = __float_as_uint(f);
  u += 0x7fffu + ((u >> 16) & 1u);
  return (u16)(u >> 16);
}

// ---------------- transpose + fp32->bf16 convert: out[c][r] = bf16(in[r][c]) ----
__global__ void k_transpose_cvt(const float* __restrict__ in, u16* __restrict__ out, int R, int C) {
  __shared__ float tile[32][33];
  int c0 = blockIdx.x * 32, r0 = blockIdx.y * 32;
  int tx = threadIdx.x, ty = threadIdx.y;
#pragma unroll
  for (int i = 0; i < 32; i += 8)
    tile[ty + i][tx] = in[(size_t)(r0 + ty + i) * C + (c0 + tx)];
  __syncthreads();
#pragma unroll
  for (int i = 0; i < 32; i += 8)
    out[(size_t)(c0 + ty + i) * R + (r0 + tx)] = f2bf(tile[tx][ty + i]);
}

// ---------------- u16 transpose per head: in [L][64] -> out [64][L] ------------
__global__ void k_transpose_u16(const u16* __restrict__ in, u16* __restrict__ out) {
  __shared__ u16 tile[32][33];
  int hd = blockIdx.z;
  int l0 = blockIdx.y * 32, d0 = blockIdx.x * 32;
  const u16* ip = in + (size_t)hd * LSEQ * DHEAD;
  u16* op = out + (size_t)hd * LSEQ * DHEAD;
  int tx = threadIdx.x, ty = threadIdx.y;
#pragma unroll
  for (int i = 0; i < 32; i += 8)
    tile[ty + i][tx] = ip[(size_t)(l0 + ty + i) * DHEAD + d0 + tx];
  __syncthreads();
#pragma unroll
  for (int i = 0; i < 32; i += 8)
    op[(size_t)(d0 + ty + i) * LSEQ + l0 + tx] = tile[tx][ty + i];
}

// ---------------- RoPE tables: cos/sin [LSEQ][32] ------------------------------
__global__ void k_rope_tables(float* __restrict__ cosb, float* __restrict__ sinb) {
  int idx = blockIdx.x * blockDim.x + threadIdx.x;
  if (idx >= LSEQ * 32) return;
  int l = idx >> 5, f = idx & 31;
  double inv = pow(10000.0, -(double)f / 32.0);
  float ang = (float)l * (float)inv;
  cosb[idx] = cosf(ang);
  sinb[idx] = sinf(ang);
}

// ---------------- segment bounds: bnd[b][s] = lower_bound(seq[b], s), s=0..4 ---
__global__ void k_bounds(const int* __restrict__ seq, int* __restrict__ bnd) {
  int t = threadIdx.x;
  if (t < BATCH * 5) {
    int b = t / 5, s = t % 5;
    const int* row = seq + b * LSEQ;
    int lo = 0, hi = LSEQ;
    while (lo < hi) { int mid = (lo + hi) >> 1; if (row[mid] < s) lo = mid + 1; else hi = mid; }
    bnd[b * 5 + s] = lo;
  }
}

// ---------------- LN1: h = bf16(layernorm(x, w, b)) ----------------------------
__global__ __launch_bounds__(256) void k_ln1(const float* __restrict__ x, const float* __restrict__ w,
                                             const float* __restrict__ bias, u16* __restrict__ h) {
  int row = blockIdx.x, t = threadIdx.x;
  const float4 xv = ((const float4*)(x + (size_t)row * DMODEL))[t];
  float s = xv.x + xv.y + xv.z + xv.w;
  float s2 = xv.x * xv.x + xv.y * xv.y + xv.z * xv.z + xv.w * xv.w;
#pragma unroll
  for (int m2 = 1; m2 < 64; m2 <<= 1) { s += __shfl_xor(s, m2); s2 += __shfl_xor(s2, m2); }
  __shared__ float rb[2][4];
  int wv = t >> 6;
  if ((t & 63) == 0) { rb[0][wv] = s; rb[1][wv] = s2; }
  __syncthreads();
  s  = rb[0][0] + rb[0][1] + rb[0][2] + rb[0][3];
  s2 = rb[1][0] + rb[1][1] + rb[1][2] + rb[1][3];
  float mu = s * (1.0f / DMODEL);
  float rs = rsqrtf(s2 * (1.0f / DMODEL) - mu * mu + 1e-5f);
  const float4 wv4 = ((const float4*)w)[t];
  const float4 bv4 = ((const float4*)bias)[t];
  ushort4 o;
  o.x = f2bf((xv.x - mu) * rs * wv4.x + bv4.x);
  o.y = f2bf((xv.y - mu) * rs * wv4.y + bv4.y);
  o.z = f2bf((xv.z - mu) * rs * wv4.z + bv4.z);
  o.w = f2bf((xv.w - mu) * rs * wv4.w + bv4.w);
  ((ushort4*)(h + (size_t)row * DMODEL))[t] = o;
}

// ---------------- bf16 GEMM: C[M][N] = A[M][K] @ BT[N][K]^T, fp32 out ----------
// m97-pattern: global_load_lds width-16 staging, pre-swizzled source, 2 barriers.
__global__ __launch_bounds__(256) void k_gemm_bt(const u16* __restrict__ A, const u16* __restrict__ B,
                                                 float* __restrict__ C, int M, int N, int K) {
  __shared__ __align__(16) u16 As[128 * 64];
  __shared__ __align__(16) u16 Bs[128 * 64];
  const int t = threadIdx.x;
  const int lane = t & 63, w = t >> 6;
  const int m0 = blockIdx.y * 128, n0 = blockIdx.x * 128;
  const int wm = (w >> 1) * 64, wn = (w & 1) * 64;
  const int NT = K >> 6;
  f32x4 acc[4][4] = {};
  const u16* Ap = A + (size_t)m0 * K;
  const u16* Bp = B + (size_t)n0 * K;
  const int cr0 = lane >> 3, cs = lane & 7;

  for (int kt = 0; kt < NT; kt++) {
#pragma unroll
    for (int s2 = 0; s2 < 4; s2++) {
      int ch = w * 4 + s2;             // 0..15
      int row = ch * 8 + cr0;          // 0..127
      int cb = cs ^ (row & 7);
      GLD((char*)As + ch * 1024, Ap + (size_t)row * K + kt * 64 + cb * 8);
      GLD((char*)Bs + ch * 1024, Bp + (size_t)row * K + kt * 64 + cb * 8);
    }
    __syncthreads();
#pragma unroll
    for (int kk = 0; kk < 2; kk++) {
      bf16x8 af[4], bfr[4];
#pragma unroll
      for (int i = 0; i < 4; i++) {
        int rowa = wm + i * 16 + (lane & 15);
        af[i] = *(const bf16x8*)((char*)As + rowa * 128 + ((kk * 64 + (lane >> 4) * 16) ^ ((rowa & 7) << 4)));
        int rowb = wn + i * 16 + (lane & 15);
        bfr[i] = *(const bf16x8*)((char*)Bs + rowb * 128 + ((kk * 64 + (lane >> 4) * 16) ^ ((rowb & 7) << 4)));
      }
#pragma unroll
      for (int mf = 0; mf < 4; mf++)
#pragma unroll
        for (int nf = 0; nf < 4; nf++)
          acc[mf][nf] = __builtin_amdgcn_mfma_f32_16x16x32_bf16(af[mf], bfr[nf], acc[mf][nf], 0, 0, 0);
    }
    __syncthreads();
  }
  const int cr = (lane >> 4) * 4, cc = lane & 15;
#pragma unroll
  for (int mf = 0; mf < 4; mf++)
#pragma unroll
    for (int nf = 0; nf < 4; nf++) {
      float* Cp = C + (size_t)(m0 + wm + mf * 16 + cr) * N + (n0 + wn + nf * 16 + cc);
#pragma unroll
      for (int r = 0; r < 4; r++) Cp[(size_t)r * N] = acc[mf][nf][r];
    }
}

// ---------------- q/k layernorm (over full D) + RoPE + split to heads ----------
__global__ __launch_bounds__(256) void k_qk_ln_rope(const float* __restrict__ qkv,
                                                    const float* __restrict__ qw, const float* __restrict__ kw,
                                                    const float* __restrict__ cosb, const float* __restrict__ sinb,
                                                    u16* __restrict__ Q, u16* __restrict__ K, u16* __restrict__ V) {
  int row = blockIdx.x, t = threadIdx.x;
  int b = row >> 11, l = row & 2047;
  const float* base = qkv + (size_t)row * 3072;
  float4 qv = ((const float4*)base)[t];
  float4 kv = ((const float4*)(base + 1024))[t];
  float4 vv = ((const float4*)(base + 2048))[t];
  float red[4];
  red[0] = qv.x + qv.y + qv.z + qv.w;
  red[1] = qv.x * qv.x + qv.y * qv.y + qv.z * qv.z + qv.w * qv.w;
  red[2] = kv.x + kv.y + kv.z + kv.w;
  red[3] = kv.x * kv.x + kv.y * kv.y + kv.z * kv.z + kv.w * kv.w;
#pragma unroll
  for (int i = 0; i < 4; i++)
#pragma unroll
    for (int m2 = 1; m2 < 64; m2 <<= 1) red[i] += __shfl_xor(red[i], m2);
  __shared__ float rb[4][4];
  int w = t >> 6;
  if ((t & 63) == 0) { rb[w][0] = red[0]; rb[w][1] = red[1]; rb[w][2] = red[2]; rb[w][3] = red[3]; }
  __syncthreads();
  float S1 = rb[0][0] + rb[1][0] + rb[2][0] + rb[3][0];
  float S2 = rb[0][1] + rb[1][1] + rb[2][1] + rb[3][1];
  float S3 = rb[0][2] + rb[1][2] + rb[2][2] + rb[3][2];
  float S4 = rb[0][3] + rb[1][3] + rb[2][3] + rb[3][3];
  float muq = S1 * (1.0f / DMODEL), rsq = rsqrtf(S2 * (1.0f / DMODEL) - muq * muq + 1e-5f);
  float muk = S3 * (1.0f / DMODEL), rsk = rsqrtf(S4 * (1.0f / DMODEL) - muk * muk + 1e-5f);
  __shared__ float qs[1024], ks[1024];
  float4 qwv = ((const float4*)qw)[t];
  float4 kwv = ((const float4*)kw)[t];
  qs[t * 4 + 0] = (qv.x - muq) * rsq * qwv.x;  ks[t * 4 + 0] = (kv.x - muk) * rsk * kwv.x;
  qs[t * 4 + 1] = (qv.y - muq) * rsq * qwv.y;  ks[t * 4 + 1] = (kv.y - muk) * rsk * kwv.y;
  qs[t * 4 + 2] = (qv.z - muq) * rsq * qwv.z;  ks[t * 4 + 2] = (kv.z - muk) * rsk * kwv.z;
  qs[t * 4 + 3] = (qv.w - muq) * rsq * qwv.w;  ks[t * 4 + 3] = (kv.w - muk) * rsk * kwv.w;
  __syncthreads();
  int d0 = t * 4;
  int hh = d0 >> 6;
  union { ushort4 v4; u16 e[4]; } qo, ko, vo;
  const float* vp = &vv.x;
#pragma unroll
  for (int i = 0; i < 4; i++) {
    int d = d0 + i, dd = d & 63, fr = dd & 31;
    float c = cosb[l * 32 + fr], s = sinb[l * 32 + fr];
    float q1 = qs[d], q2 = (dd < 32) ? -qs[d + 32] : qs[d - 32];
    float k1 = ks[d], k2 = (dd < 32) ? -ks[d + 32] : ks[d - 32];
    qo.e[i] = f2bf(q1 * c + q2 * s);
    ko.e[i] = f2bf(k1 * c + k2 * s);
    vo.e[i] = f2bf(vp[i]);
  }
  size_t oidx = ((size_t)(b * NHEAD + hh) * LSEQ + l) * DHEAD + (d0 & 63);
  *(ushort4*)(Q + oidx) = qo.v4;
  *(ushort4*)(K + oidx) = ko.v4;
  *(ushort4*)(V + oidx) = vo.v4;
}

// ---------------- segment-masked flash attention (swapped-QK, fixed-shift SM) --
// block = 64 q-rows, 4 waves x 16 q-rows. K,V^T double-buffered via gload_lds.
__global__ __launch_bounds__(256) void k_attn(const u16* __restrict__ Q, const u16* __restrict__ Kb,
                                              const u16* __restrict__ VTb, const int* __restrict__ seq,
                                              const int* __restrict__ bnd, u16* __restrict__ ctx) {
  __shared__ __align__(16) u16 Ks[2][64 * 64];
  __shared__ __align__(16) u16 Vs[2][64 * 64];
  __shared__ __align__(16) u16 Pw[4][16 * 64];

  const int bid = blockIdx.x;
  const int qt = bid & 31, h = (bid >> 5) & 15, b = bid >> 9;
  const int t = threadIdx.x, l = t & 63, w = t >> 6;
  const int c = l & 15, g = l >> 4;
  const int q0 = qt * 64;
  const size_t hoff = (size_t)(b * NHEAD + h) * LSEQ * DHEAD;
  const u16* Qg = Q + hoff;
  const u16* Kg = Kb + hoff;
  const u16* Vg = VTb + hoff;   // [d][l]
  const int* seqb = seq + b * LSEQ;
  const int* bnd5 = bnd + b * 5;

  const int qw0 = q0 + w * 16;
  const int myq = qw0 + c;
  const int sq = seqb[myq];
  const int lo = bnd5[sq], hi = bnd5[sq + 1];
  const int wlo = bnd5[seqb[qw0]];
  const int whi = bnd5[seqb[qw0 + 15] + 1];
  int kbeg = bnd5[seqb[q0]] & ~63;
  int kend = (bnd5[seqb[q0 + 63] + 1] + 63) & ~63;
  if (kend > LSEQ) kend = LSEQ;

  bf16x8 qf[2];
  qf[0] = *(const bf16x8*)(Qg + (size_t)myq * 64 + g * 8);
  qf[1] = *(const bf16x8*)(Qg + (size_t)myq * 64 + 32 + g * 8);

  f32x4 acc[4] = {};
  float lsum = 0.f;

#define STAGE(bb, kt_) do { \
    int r1 = w * 16 + (l >> 3); \
    int r2 = r1 + 8; \
    GLD((char*)Ks[bb] + (w * 2    ) * 1024, Kg + (size_t)((kt_) + r1) * 64 + (((l & 7) ^ (r1 & 7)) * 8)); \
    GLD((char*)Ks[bb] + (w * 2 + 1) * 1024, Kg + (size_t)((kt_) + r2) * 64 + (((l & 7) ^ (r2 & 7)) * 8)); \
    GLD((char*)Vs[bb] + (w * 2    ) * 1024, Vg + (size_t)r1 * LSEQ + (kt_) + (((l & 7) ^ (r1 & 7)) * 8)); \
    GLD((char*)Vs[bb] + (w * 2 + 1) * 1024, Vg + (size_t)r2 * LSEQ + (kt_) + (((l & 7) ^ (r2 & 7)) * 8)); \
  } while (0)

  STAGE(0, kbeg);
  int cur = 0;
  for (int kt = kbeg; kt < kend; kt += 64) {
    const bool more = (kt + 64) < kend;
    if (more) STAGE(cur ^ 1, kt + 64);
    if (more) asm volatile("s_waitcnt vmcnt(4)" ::: "memory");
    else      asm volatile("s_waitcnt vmcnt(0)" ::: "memory");
    __builtin_amdgcn_s_barrier();
    __builtin_amdgcn_sched_barrier(0);
    if (kt < whi && kt + 64 > wlo) {
      const u16* ksb = Ks[cur];
      const u16* vsb = Vs[cur];
      // QK^T swapped: st[i][r] = S^T[k_local = i*16+g*4+r][q = qw0+c]
      f32x4 st[4] = {};
#pragma unroll
      for (int kk = 0; kk < 2; kk++) {
        bf16x8 kf[4];
#pragma unroll
        for (int i = 0; i < 4; i++) {
          int row = i * 16 + c;
          kf[i] = *(const bf16x8*)((const char*)ksb + row * 128 + ((kk * 64 + g * 16) ^ ((row & 7) << 4)));
        }
#pragma unroll
        for (int i = 0; i < 4; i++)
          st[i] = __builtin_amdgcn_mfma_f32_16x16x32_bf16(kf[i], qf[kk], st[i], 0, 0, 0);
      }
      // fixed-shift softmax: p = exp(s/8 - 8); masked -> 0. No online max needed.
      const int kb0 = kt + g * 4;
#pragma unroll
      for (int i = 0; i < 4; i++) {
        float p[4];
#pragma unroll
        for (int r = 0; r < 4; r++) {
          int kglob = kb0 + i * 16 + r;
          bool ok = ((unsigned)(kglob - lo)) < ((unsigned)(hi - lo));
          float x = ok ? fmaf(st[i][r], 0.125f, -8.0f) : -1e30f;
          p[r] = __expf(x);
          lsum += p[r];
        }
        unsigned w0, w1;
        asm("v_cvt_pk_bf16_f32 %0, %1, %2" : "=v"(w0) : "v"(p[0]), "v"(p[1]));
        asm("v_cvt_pk_bf16_f32 %0, %1, %2" : "=v"(w1) : "v"(p[2]), "v"(p[3]));
        uint2 wp; wp.x = w0; wp.y = w1;
        *(uint2*)((char*)Pw[w] + c * 128 + ((i * 32 + g * 8) ^ ((c & 3) << 4))) = wp;
      }
      // PV: acc[df][r] = out[q = qw0+g*4+r][d = df*16+c]
#pragma unroll
      for (int kk = 0; kk < 2; kk++) {
        bf16x8 pa = *(const bf16x8*)((char*)Pw[w] + c * 128 + ((kk * 64 + g * 16) ^ ((c & 3) << 4)));
        bf16x8 vf[4];
#pragma unroll
        for (int df = 0; df < 4; df++) {
          int row = df * 16 + c;
          vf[df] = *(const bf16x8*)((const char*)vsb + row * 128 + ((kk * 64 + g * 16) ^ ((row & 7) << 4)));
        }
#pragma unroll
        for (int df = 0; df < 4; df++)
          acc[df] = __builtin_amdgcn_mfma_f32_16x16x32_bf16(pa, vf[df], acc[df], 0, 0, 0);
      }
    }
    __builtin_amdgcn_sched_barrier(0);
    __builtin_amdgcn_s_barrier();
    cur ^= 1;
  }
#undef STAGE

  lsum += __shfl_xor(lsum, 16);
  lsum += __shfl_xor(lsum, 32);
#pragma unroll
  for (int r = 0; r < 4; r++) {
    float lr = __shfl(lsum, g * 4 + r, 64);
    float rls = 1.0f / lr;
    int qrow = qw0 + g * 4 + r;
    u16* op = ctx + (size_t)(b * LSEQ + qrow) * DMODEL + h * 64 + c;
#pragma unroll
    for (int df = 0; df < 4; df++)
      op[df * 16] = f2bf(acc[df][r] * rls);
  }
}

// ---------------- launch --------------------------------------------------------
extern "C" void kernel_launch(void* const* d_in, const int* in_sizes, int n_in,
                              void* d_out, int out_size, void* d_ws, size_t ws_size,
                              hipStream_t stream) {
  const float* x    = (const float*)d_in[0];
  const int*   seq  = (const int*)d_in[1];
  const float* ln1w = (const float*)d_in[2];
  const float* ln1b = (const float*)d_in[3];
  const float* wqkv = (const float*)d_in[4];
  const float* qlnw = (const float*)d_in[5];
  const float* klnw = (const float*)d_in[6];
  const float* wout = (const float*)d_in[7];
  float* out = (float*)d_out;

  char* p = (char*)d_ws;
  u16* wqkvT = (u16*)p;  p += (size_t)3072 * 1024 * 2;
  u16* woutT = (u16*)p;  p += (size_t)1024 * 1024 * 2;
  u16* hbuf  = (u16*)p;  p += (size_t)ROWS * DMODEL * 2;
  u16* Qb    = (u16*)p;  p += (size_t)ROWS * DMODEL * 2;
  u16* Kbuf  = (u16*)p;  p += (size_t)ROWS * DMODEL * 2;
  u16* Vbuf  = (u16*)p;  p += (size_t)ROWS * DMODEL * 2;
  u16* VTbuf = (u16*)p;  p += (size_t)ROWS * DMODEL * 2;
  u16* ctxb  = (u16*)p;  p += (size_t)ROWS * DMODEL * 2;
  float* cosb = (float*)p; p += (size_t)LSEQ * 32 * 4;
  float* sinb = (float*)p; p += (size_t)LSEQ * 32 * 4;
  int* bnd   = (int*)p;  p += 256;
  float* qkv = (float*)p; p += (size_t)ROWS * 3072 * 4;

  k_transpose_cvt<<<dim3(3072 / 32, 1024 / 32), dim3(32, 8), 0, stream>>>(wqkv, wqkvT, 1024, 3072);
  k_transpose_cvt<<<dim3(1024 / 32, 1024 / 32), dim3(32, 8), 0, stream>>>(wout, woutT, 1024, 1024);
  k_rope_tables<<<(LSEQ * 32) / 256, 256, 0, stream>>>(cosb, sinb);
  k_bounds<<<1, 64, 0, stream>>>(seq, bnd);
  k_ln1<<<ROWS, 256, 0, stream>>>(x, ln1w, ln1b, hbuf);
  k_gemm_bt<<<dim3(3072 / 128, ROWS / 128), 256, 0, stream>>>(hbuf, wqkvT, qkv, ROWS, 3072, 1024);
  k_qk_ln_rope<<<ROWS, 256, 0, stream>>>(qkv, qlnw, klnw, cosb, sinb, Qb, Kbuf, Vbuf);
  k_transpose_u16<<<dim3(DHEAD / 32, LSEQ / 32, BATCH * NHEAD), dim3(32, 8), 0, stream>>>(Vbuf, VTbuf);
  k_attn<<<BATCH * NHEAD * (LSEQ / 64), 256, 0, stream>>>(Qb, Kbuf, VTbuf, seq, bnd, ctxb);
  k_gemm_bt<<<dim3(1024 / 128, ROWS / 128), 256, 0, stream>>>(ctxb, woutT, out, ROWS, 1024, 1024);
}

// Round 3
// 138.571 us; speedup vs baseline: 1.1027x; 1.0665x over previous
//
#include <hip/hip_runtime.h>
#include <hip/hip_bf16.h>
#include <cstdint>
#include <math.h>

#define LSEQ 2048
#define BATCH 2
#define NHEAD 16
#define DHEAD 64
#define DMODEL 1024
#define ROWS (BATCH*LSEQ)

typedef __bf16 bf16x8 __attribute__((ext_vector_type(8)));
typedef float f32x4 __attribute__((ext_vector_type(4)));
typedef unsigned short u16;

#define GLD(lds_base, src_g) \
  __builtin_amdgcn_global_load_lds((const __attribute__((address_space(1))) void*)(src_g), \
                                   (__attribute__((address_space(3))) void*)(lds_base), 16, 0, 0)

__device__ __forceinline__ u16 f2bf(float f) {
  unsigned int u = __float_as_uint(f);
  u += 0x7fffu + ((u >> 16) & 1u);
  return (u16)(u >> 16);
}
__device__ __forceinline__ float bf2f(u16 u) {
  return __uint_as_float(((unsigned)u) << 16);
}

// ---------------- transpose + fp32->bf16 convert: out[c][r] = bf16(in[r][c]) ----
__global__ void k_transpose_cvt(const float* __restrict__ in, u16* __restrict__ out, int R, int C) {
  __shared__ float tile[32][33];
  int c0 = blockIdx.x * 32, r0 = blockIdx.y * 32;
  int tx = threadIdx.x, ty = threadIdx.y;
#pragma unroll
  for (int i = 0; i < 32; i += 8)
    tile[ty + i][tx] = in[(size_t)(r0 + ty + i) * C + (c0 + tx)];
  __syncthreads();
#pragma unroll
  for (int i = 0; i < 32; i += 8)
    out[(size_t)(c0 + ty + i) * R + (r0 + tx)] = f2bf(tile[tx][ty + i]);
}

// ---------------- u16 transpose per head: in [L][64] -> out [64][L] ------------
__global__ void k_transpose_u16(const u16* __restrict__ in, u16* __restrict__ out) {
  __shared__ u16 tile[32][33];
  int hd = blockIdx.z;
  int l0 = blockIdx.y * 32, d0 = blockIdx.x * 32;
  const u16* ip = in + (size_t)hd * LSEQ * DHEAD;
  u16* op = out + (size_t)hd * LSEQ * DHEAD;
  int tx = threadIdx.x, ty = threadIdx.y;
#pragma unroll
  for (int i = 0; i < 32; i += 8)
    tile[ty + i][tx] = ip[(size_t)(l0 + ty + i) * DHEAD + d0 + tx];
  __syncthreads();
#pragma unroll
  for (int i = 0; i < 32; i += 8)
    op[(size_t)(d0 + ty + i) * LSEQ + l0 + tx] = tile[tx][ty + i];
}

// ---------------- RoPE tables + segment bounds (fused) -------------------------
__global__ void k_rope_tables(float* __restrict__ cosb, float* __restrict__ sinb,
                              const int* __restrict__ seq, int* __restrict__ bnd) {
  if (blockIdx.x == 0 && threadIdx.x < BATCH * 5) {
    int b = threadIdx.x / 5, s = threadIdx.x % 5;
    const int* row = seq + b * LSEQ;
    int lo = 0, hi = LSEQ;
    while (lo < hi) { int mid = (lo + hi) >> 1; if (row[mid] < s) lo = mid + 1; else hi = mid; }
    bnd[b * 5 + s] = lo;
  }
  int idx = blockIdx.x * blockDim.x + threadIdx.x;
  if (idx >= LSEQ * 32) return;
  int l = idx >> 5, f = idx & 31;
  double inv = pow(10000.0, -(double)f / 32.0);
  float ang = (float)l * (float)inv;
  cosb[idx] = cosf(ang);
  sinb[idx] = sinf(ang);
}

// ---------------- LN1: h = bf16(layernorm(x, w, b)) ----------------------------
__global__ __launch_bounds__(256) void k_ln1(const float* __restrict__ x, const float* __restrict__ w,
                                             const float* __restrict__ bias, u16* __restrict__ h) {
  int row = blockIdx.x, t = threadIdx.x;
  const float4 xv = ((const float4*)(x + (size_t)row * DMODEL))[t];
  float s = xv.x + xv.y + xv.z + xv.w;
  float s2 = xv.x * xv.x + xv.y * xv.y + xv.z * xv.z + xv.w * xv.w;
#pragma unroll
  for (int m2 = 1; m2 < 64; m2 <<= 1) { s += __shfl_xor(s, m2); s2 += __shfl_xor(s2, m2); }
  __shared__ float rb[2][4];
  int wv = t >> 6;
  if ((t & 63) == 0) { rb[0][wv] = s; rb[1][wv] = s2; }
  __syncthreads();
  s  = rb[0][0] + rb[0][1] + rb[0][2] + rb[0][3];
  s2 = rb[1][0] + rb[1][1] + rb[1][2] + rb[1][3];
  float mu = s * (1.0f / DMODEL);
  float rs = rsqrtf(s2 * (1.0f / DMODEL) - mu * mu + 1e-5f);
  const float4 wv4 = ((const float4*)w)[t];
  const float4 bv4 = ((const float4*)bias)[t];
  ushort4 o;
  o.x = f2bf((xv.x - mu) * rs * wv4.x + bv4.x);
  o.y = f2bf((xv.y - mu) * rs * wv4.y + bv4.y);
  o.z = f2bf((xv.z - mu) * rs * wv4.z + bv4.z);
  o.w = f2bf((xv.w - mu) * rs * wv4.w + bv4.w);
  ((ushort4*)(h + (size_t)row * DMODEL))[t] = o;
}

// ---------------- bf16 GEMM: C[M][N] = A[M][K] @ BT[N][K]^T --------------------
// 2-phase pipelined: STAGE(next) issued before compute(cur); one vmcnt(0)+barrier
// per K-step (catalog T3-minimum). OUTMODE: 0 = f32 out, 1 = bf16 out.
template<int OUTMODE>
__global__ __launch_bounds__(256) void k_gemm_bt(const u16* __restrict__ A, const u16* __restrict__ B,
                                                 void* __restrict__ Cv, int M, int N, int K) {
  __shared__ __align__(16) u16 As[2][128 * 64];
  __shared__ __align__(16) u16 Bs[2][128 * 64];
  const int t = threadIdx.x;
  const int lane = t & 63, w = t >> 6;
  const int m0 = blockIdx.y * 128, n0 = blockIdx.x * 128;
  const int wm = (w >> 1) * 64, wn = (w & 1) * 64;
  const int NT = K >> 6;
  f32x4 acc[4][4] = {};
  const u16* Ap = A + (size_t)m0 * K;
  const u16* Bp = B + (size_t)n0 * K;
  const int cr0 = lane >> 3, cs = lane & 7;

#define GSTAGE(bb, kt_) do { \
    _Pragma("unroll") \
    for (int s2 = 0; s2 < 4; s2++) { \
      int ch = w * 4 + s2; \
      int row = ch * 8 + cr0; \
      int cb = cs ^ (row & 7); \
      GLD((char*)As[bb] + ch * 1024, Ap + (size_t)row * K + (kt_) * 64 + cb * 8); \
      GLD((char*)Bs[bb] + ch * 1024, Bp + (size_t)row * K + (kt_) * 64 + cb * 8); \
    } } while (0)

  GSTAGE(0, 0);
  asm volatile("s_waitcnt vmcnt(0)" ::: "memory");
  __builtin_amdgcn_s_barrier();
  int cur = 0;
  for (int kt = 0; kt < NT; kt++) {
    if (kt + 1 < NT) GSTAGE(cur ^ 1, kt + 1);
    const u16* asb = As[cur];
    const u16* bsb = Bs[cur];
#pragma unroll
    for (int kk = 0; kk < 2; kk++) {
      bf16x8 af[4], bfr[4];
#pragma unroll
      for (int i = 0; i < 4; i++) {
        int rowa = wm + i * 16 + (lane & 15);
        af[i] = *(const bf16x8*)((const char*)asb + rowa * 128 + ((kk * 64 + (lane >> 4) * 16) ^ ((rowa & 7) << 4)));
        int rowb = wn + i * 16 + (lane & 15);
        bfr[i] = *(const bf16x8*)((const char*)bsb + rowb * 128 + ((kk * 64 + (lane >> 4) * 16) ^ ((rowb & 7) << 4)));
      }
#pragma unroll
      for (int mf = 0; mf < 4; mf++)
#pragma unroll
        for (int nf = 0; nf < 4; nf++)
          acc[mf][nf] = __builtin_amdgcn_mfma_f32_16x16x32_bf16(af[mf], bfr[nf], acc[mf][nf], 0, 0, 0);
    }
    asm volatile("s_waitcnt vmcnt(0)" ::: "memory");
    __builtin_amdgcn_s_barrier();
    cur ^= 1;
  }
#undef GSTAGE
  const int cr = (lane >> 4) * 4, cc = lane & 15;
#pragma unroll
  for (int mf = 0; mf < 4; mf++)
#pragma unroll
    for (int nf = 0; nf < 4; nf++) {
      if (OUTMODE == 0) {
        float* Cp = (float*)Cv + (size_t)(m0 + wm + mf * 16 + cr) * N + (n0 + wn + nf * 16 + cc);
#pragma unroll
        for (int r = 0; r < 4; r++) Cp[(size_t)r * N] = acc[mf][nf][r];
      } else {
        u16* Cp = (u16*)Cv + (size_t)(m0 + wm + mf * 16 + cr) * N + (n0 + wn + nf * 16 + cc);
#pragma unroll
        for (int r = 0; r < 4; r++) Cp[(size_t)r * N] = f2bf(acc[mf][nf][r]);
      }
    }
}

// ---------------- q/k layernorm (over full D, bf16 in) + RoPE + head split -----
__global__ __launch_bounds__(256) void k_qk_ln_rope(const u16* __restrict__ qkv,
                                                    const float* __restrict__ qw, const float* __restrict__ kw,
                                                    const float* __restrict__ cosb, const float* __restrict__ sinb,
                                                    u16* __restrict__ Q, u16* __restrict__ K, u16* __restrict__ V) {
  int row = blockIdx.x, t = threadIdx.x;
  int b = row >> 11, l = row & 2047;
  const u16* base = qkv + (size_t)row * 3072;
  ushort4 qu = ((const ushort4*)base)[t];
  ushort4 ku = ((const ushort4*)(base + 1024))[t];
  ushort4 vu = ((const ushort4*)(base + 2048))[t];
  float qx = bf2f(qu.x), qy = bf2f(qu.y), qz = bf2f(qu.z), qw_ = bf2f(qu.w);
  float kx = bf2f(ku.x), ky = bf2f(ku.y), kz = bf2f(ku.z), kw_ = bf2f(ku.w);
  float red[4];
  red[0] = qx + qy + qz + qw_;
  red[1] = qx * qx + qy * qy + qz * qz + qw_ * qw_;
  red[2] = kx + ky + kz + kw_;
  red[3] = kx * kx + ky * ky + kz * kz + kw_ * kw_;
#pragma unroll
  for (int i = 0; i < 4; i++)
#pragma unroll
    for (int m2 = 1; m2 < 64; m2 <<= 1) red[i] += __shfl_xor(red[i], m2);
  __shared__ float rb[4][4];
  int w = t >> 6;
  if ((t & 63) == 0) { rb[w][0] = red[0]; rb[w][1] = red[1]; rb[w][2] = red[2]; rb[w][3] = red[3]; }
  __syncthreads();
  float S1 = rb[0][0] + rb[1][0] + rb[2][0] + rb[3][0];
  float S2 = rb[0][1] + rb[1][1] + rb[2][1] + rb[3][1];
  float S3 = rb[0][2] + rb[1][2] + rb[2][2] + rb[3][2];
  float S4 = rb[0][3] + rb[1][3] + rb[2][3] + rb[3][3];
  float muq = S1 * (1.0f / DMODEL), rsq = rsqrtf(S2 * (1.0f / DMODEL) - muq * muq + 1e-5f);
  float muk = S3 * (1.0f / DMODEL), rsk = rsqrtf(S4 * (1.0f / DMODEL) - muk * muk + 1e-5f);
  __shared__ float qs[1024], ks[1024];
  float4 qwv = ((const float4*)qw)[t];
  float4 kwv = ((const float4*)kw)[t];
  qs[t * 4 + 0] = (qx - muq) * rsq * qwv.x;  ks[t * 4 + 0] = (kx - muk) * rsk * kwv.x;
  qs[t * 4 + 1] = (qy - muq) * rsq * qwv.y;  ks[t * 4 + 1] = (ky - muk) * rsk * kwv.y;
  qs[t * 4 + 2] = (qz - muq) * rsq * qwv.z;  ks[t * 4 + 2] = (kz - muk) * rsk * kwv.z;
  qs[t * 4 + 3] = (qw_ - muq) * rsq * qwv.w; ks[t * 4 + 3] = (kw_ - muk) * rsk * kwv.w;
  __syncthreads();
  int d0 = t * 4;
  int hh = d0 >> 6;
  union { ushort4 v4; u16 e[4]; } qo, ko;
#pragma unroll
  for (int i = 0; i < 4; i++) {
    int d = d0 + i, dd = d & 63, fr = dd & 31;
    float c = cosb[l * 32 + fr], s = sinb[l * 32 + fr];
    float q1 = qs[d], q2 = (dd < 32) ? -qs[d + 32] : qs[d - 32];
    float k1 = ks[d], k2 = (dd < 32) ? -ks[d + 32] : ks[d - 32];
    qo.e[i] = f2bf(q1 * c + q2 * s);
    ko.e[i] = f2bf(k1 * c + k2 * s);
  }
  size_t oidx = ((size_t)(b * NHEAD + hh) * LSEQ + l) * DHEAD + (d0 & 63);
  *(ushort4*)(Q + oidx) = qo.v4;
  *(ushort4*)(K + oidx) = ko.v4;
  *(ushort4*)(V + oidx) = vu;
}

// ---------------- segment-masked flash attention (swapped-QK, fixed-shift SM) --
__global__ __launch_bounds__(256) void k_attn(const u16* __restrict__ Q, const u16* __restrict__ Kb,
                                              const u16* __restrict__ VTb, const int* __restrict__ seq,
                                              const int* __restrict__ bnd, u16* __restrict__ ctx) {
  __shared__ __align__(16) u16 Ks[2][64 * 64];
  __shared__ __align__(16) u16 Vs[2][64 * 64];
  __shared__ __align__(16) u16 Pw[4][16 * 64];

  const int bid = blockIdx.x;
  const int qt = bid & 31, h = (bid >> 5) & 15, b = bid >> 9;
  const int t = threadIdx.x, l = t & 63, w = t >> 6;
  const int c = l & 15, g = l >> 4;
  const int q0 = qt * 64;
  const size_t hoff = (size_t)(b * NHEAD + h) * LSEQ * DHEAD;
  const u16* Qg = Q + hoff;
  const u16* Kg = Kb + hoff;
  const u16* Vg = VTb + hoff;   // [d][l]
  const int* seqb = seq + b * LSEQ;
  const int* bnd5 = bnd + b * 5;

  const int qw0 = q0 + w * 16;
  const int myq = qw0 + c;
  const int sq = seqb[myq];
  const int lo = bnd5[sq], hi = bnd5[sq + 1];
  const int wlo = bnd5[seqb[qw0]];
  const int whi = bnd5[seqb[qw0 + 15] + 1];
  int kbeg = bnd5[seqb[q0]] & ~63;
  int kend = (bnd5[seqb[q0 + 63] + 1] + 63) & ~63;
  if (kend > LSEQ) kend = LSEQ;

  bf16x8 qf[2];
  qf[0] = *(const bf16x8*)(Qg + (size_t)myq * 64 + g * 8);
  qf[1] = *(const bf16x8*)(Qg + (size_t)myq * 64 + 32 + g * 8);

  f32x4 acc[4] = {};
  float lsum = 0.f;

#define STAGE(bb, kt_) do { \
    int r1 = w * 16 + (l >> 3); \
    int r2 = r1 + 8; \
    GLD((char*)Ks[bb] + (w * 2    ) * 1024, Kg + (size_t)((kt_) + r1) * 64 + (((l & 7) ^ (r1 & 7)) * 8)); \
    GLD((char*)Ks[bb] + (w * 2 + 1) * 1024, Kg + (size_t)((kt_) + r2) * 64 + (((l & 7) ^ (r2 & 7)) * 8)); \
    GLD((char*)Vs[bb] + (w * 2    ) * 1024, Vg + (size_t)r1 * LSEQ + (kt_) + (((l & 7) ^ (r1 & 7)) * 8)); \
    GLD((char*)Vs[bb] + (w * 2 + 1) * 1024, Vg + (size_t)r2 * LSEQ + (kt_) + (((l & 7) ^ (r2 & 7)) * 8)); \
  } while (0)

  STAGE(0, kbeg);
  int cur = 0;
  for (int kt = kbeg; kt < kend; kt += 64) {
    const bool more = (kt + 64) < kend;
    if (more) STAGE(cur ^ 1, kt + 64);
    if (more) asm volatile("s_waitcnt vmcnt(4)" ::: "memory");
    else      asm volatile("s_waitcnt vmcnt(0)" ::: "memory");
    __builtin_amdgcn_s_barrier();
    __builtin_amdgcn_sched_barrier(0);
    if (kt < whi && kt + 64 > wlo) {
      const u16* ksb = Ks[cur];
      const u16* vsb = Vs[cur];
      f32x4 st[4] = {};
#pragma unroll
      for (int kk = 0; kk < 2; kk++) {
        bf16x8 kf[4];
#pragma unroll
        for (int i = 0; i < 4; i++) {
          int row = i * 16 + c;
          kf[i] = *(const bf16x8*)((const char*)ksb + row * 128 + ((kk * 64 + g * 16) ^ ((row & 7) << 4)));
        }
#pragma unroll
        for (int i = 0; i < 4; i++)
          st[i] = __builtin_amdgcn_mfma_f32_16x16x32_bf16(kf[i], qf[kk], st[i], 0, 0, 0);
      }
      const int kb0 = kt + g * 4;
#pragma unroll
      for (int i = 0; i < 4; i++) {
        float p[4];
#pragma unroll
        for (int r = 0; r < 4; r++) {
          int kglob = kb0 + i * 16 + r;
          bool ok = ((unsigned)(kglob - lo)) < ((unsigned)(hi - lo));
          float x = ok ? fmaf(st[i][r], 0.125f, -8.0f) : -1e30f;
          p[r] = __expf(x);
          lsum += p[r];
        }
        unsigned w0, w1;
        asm("v_cvt_pk_bf16_f32 %0, %1, %2" : "=v"(w0) : "v"(p[0]), "v"(p[1]));
        asm("v_cvt_pk_bf16_f32 %0, %1, %2" : "=v"(w1) : "v"(p[2]), "v"(p[3]));
        uint2 wp; wp.x = w0; wp.y = w1;
        *(uint2*)((char*)Pw[w] + c * 128 + ((i * 32 + g * 8) ^ ((c & 3) << 4))) = wp;
      }
#pragma unroll
      for (int kk = 0; kk < 2; kk++) {
        bf16x8 pa = *(const bf16x8*)((char*)Pw[w] + c * 128 + ((kk * 64 + g * 16) ^ ((c & 3) << 4)));
        bf16x8 vf[4];
#pragma unroll
        for (int df = 0; df < 4; df++) {
          int row = df * 16 + c;
          vf[df] = *(const bf16x8*)((const char*)vsb + row * 128 + ((kk * 64 + g * 16) ^ ((row & 7) << 4)));
        }
#pragma unroll
        for (int df = 0; df < 4; df++)
          acc[df] = __builtin_amdgcn_mfma_f32_16x16x32_bf16(pa, vf[df], acc[df], 0, 0, 0);
      }
    }
    __builtin_amdgcn_sched_barrier(0);
    __builtin_amdgcn_s_barrier();
    cur ^= 1;
  }
#undef STAGE

  lsum += __shfl_xor(lsum, 16);
  lsum += __shfl_xor(lsum, 32);
#pragma unroll
  for (int r = 0; r < 4; r++) {
    float lr = __shfl(lsum, g * 4 + r, 64);
    float rls = 1.0f / lr;
    int qrow = qw0 + g * 4 + r;
    u16* op = ctx + (size_t)(b * LSEQ + qrow) * DMODEL + h * 64 + c;
#pragma unroll
    for (int df = 0; df < 4; df++)
      op[df * 16] = f2bf(acc[df][r] * rls);
  }
}

// ---------------- launch --------------------------------------------------------
extern "C" void kernel_launch(void* const* d_in, const int* in_sizes, int n_in,
                              void* d_out, int out_size, void* d_ws, size_t ws_size,
                              hipStream_t stream) {
  const float* x    = (const float*)d_in[0];
  const int*   seq  = (const int*)d_in[1];
  const float* ln1w = (const float*)d_in[2];
  const float* ln1b = (const float*)d_in[3];
  const float* wqkv = (const float*)d_in[4];
  const float* qlnw = (const float*)d_in[5];
  const float* klnw = (const float*)d_in[6];
  const float* wout = (const float*)d_in[7];
  float* out = (float*)d_out;

  char* p = (char*)d_ws;
  u16* wqkvT = (u16*)p;  p += (size_t)3072 * 1024 * 2;
  u16* woutT = (u16*)p;  p += (size_t)1024 * 1024 * 2;
  u16* hbuf  = (u16*)p;  p += (size_t)ROWS * DMODEL * 2;
  u16* Qb    = (u16*)p;  p += (size_t)ROWS * DMODEL * 2;
  u16* Kbuf  = (u16*)p;  p += (size_t)ROWS * DMODEL * 2;
  u16* Vbuf  = (u16*)p;  p += (size_t)ROWS * DMODEL * 2;
  u16* VTbuf = (u16*)p;  p += (size_t)ROWS * DMODEL * 2;
  u16* ctxb  = (u16*)p;  p += (size_t)ROWS * DMODEL * 2;
  float* cosb = (float*)p; p += (size_t)LSEQ * 32 * 4;
  float* sinb = (float*)p; p += (size_t)LSEQ * 32 * 4;
  int* bnd   = (int*)p;  p += 256;
  u16* qkv   = (u16*)p;  p += (size_t)ROWS * 3072 * 2;

  k_transpose_cvt<<<dim3(3072 / 32, 1024 / 32), dim3(32, 8), 0, stream>>>(wqkv, wqkvT, 1024, 3072);
  k_transpose_cvt<<<dim3(1024 / 32, 1024 / 32), dim3(32, 8), 0, stream>>>(wout, woutT, 1024, 1024);
  k_rope_tables<<<(LSEQ * 32) / 256, 256, 0, stream>>>(cosb, sinb, seq, bnd);
  k_ln1<<<ROWS, 256, 0, stream>>>(x, ln1w, ln1b, hbuf);
  k_gemm_bt<1><<<dim3(3072 / 128, ROWS / 128), 256, 0, stream>>>(hbuf, wqkvT, (void*)qkv, ROWS, 3072, 1024);
  k_qk_ln_rope<<<ROWS, 256, 0, stream>>>(qkv, qlnw, klnw, cosb, sinb, Qb, Kbuf, Vbuf);
  k_transpose_u16<<<dim3(DHEAD / 32, LSEQ / 32, BATCH * NHEAD), dim3(32, 8), 0, stream>>>(Vbuf, VTbuf);
  k_attn<<<BATCH * NHEAD * (LSEQ / 64), 256, 0, stream>>>(Qb, Kbuf, VTbuf, seq, bnd, ctxb);
  k_gemm_bt<0><<<dim3(1024 / 128, ROWS / 128), 256, 0, stream>>>(ctxb, woutT, (void*)out, ROWS, 1024, 1024);
}